// Round 2
// 977.867 us; speedup vs baseline: 1.0406x; 1.0406x over previous
//
#include <hip/hip_runtime.h>
#include <hip/hip_bf16.h>

#define N_NODES 10000
#define N_EDGES 640000
#define HD 128          // NUM_HEADS * OUT_DIM
#define NH 8
#define TPAD 136        // LDS row pad: 272B stride -> uniform bank spread on b128 reads

typedef __attribute__((ext_vector_type(4))) float floatx4;
typedef __attribute__((ext_vector_type(8))) __bf16 bf16x8;

__device__ __forceinline__ float b2f(unsigned short u) {
    union { unsigned int i; float f; } x;
    x.i = ((unsigned int)u) << 16;
    return x.f;
}
__device__ __forceinline__ unsigned short f2b(float f) {   // RNE bf16
    union { float f; unsigned int i; } x; x.f = f;
    unsigned int r = x.i + 0x7FFF + ((x.i >> 16) & 1);
    return (unsigned short)(r >> 16);
}

template<bool F32>
__device__ __forceinline__ float ld1(const void* p, size_t i) {
    if (F32) return ((const float*)p)[i];
    return b2f(((const unsigned short*)p)[i]);
}
template<bool F32>
__device__ __forceinline__ void ld8(const void* p, size_t i, float* out) {
    if (F32) {
        floatx4 a = *(const floatx4*)((const float*)p + i);
        floatx4 b = *(const floatx4*)((const float*)p + i + 4);
        out[0]=a[0]; out[1]=a[1]; out[2]=a[2]; out[3]=a[3];
        out[4]=b[0]; out[5]=b[1]; out[6]=b[2]; out[7]=b[3];
    } else {
        uint4 u = *(const uint4*)((const unsigned short*)p + i);
        const unsigned short* s = (const unsigned short*)&u;
        #pragma unroll
        for (int j = 0; j < 8; ++j) out[j] = b2f(s[j]);
    }
}
// load 8 elems -> packed bf16 (uint4)
template<bool F32>
__device__ __forceinline__ uint4 ld8b(const void* p, size_t i) {
    if (F32) {
        float f[8]; ld8<true>(p, i, f);
        union { unsigned short s[8]; uint4 u; } r;
        #pragma unroll
        for (int j = 0; j < 8; ++j) r.s[j] = f2b(f[j]);
        return r.u;
    }
    return *(const uint4*)((const unsigned short*)p + i);
}

// ---------------- Kernel 0: dtype sniff (1 block) ----------------
__global__ void k_sniff(const unsigned short* __restrict__ h,
                        int* __restrict__ wcnt, int* __restrict__ flag) {
    int t = threadIdx.x;
    int w = 0;
    #pragma unroll
    for (int j = 0; j < 16; ++j) {
        unsigned short u = h[t * 16 + j];
        int ex = (u >> 7) & 0xFF;
        if (ex >= 0x8F) ++w;
    }
    atomicAdd(wcnt, w);
    __threadfence();
    __syncthreads();
    if (t == 0) {
        int c = atomicAdd(wcnt, 0);
        *flag = (c > 64) ? 1 : 0;   // 1 => inputs (and output) are fp32
    }
}

// ---------------- Kernel 0b: transpose Wq/Wk/Wv -> fp32 WT --------------
// WT[c][d] = W[d][c]; makes k_qkv's W reads coalesced (1 line per wave-load
// instead of 64).
template<bool F32>
__device__ __forceinline__ void wt_body(float (*tile)[33], const void* W,
                                        float* __restrict__ WT) {
    const int t  = blockIdx.x & 15;          // 4x4 tiles of 32x32
    const int tr = t >> 2, tc = t & 3;
    const int cx = threadIdx.x & 31, ry = threadIdx.x >> 5;   // 32 x 8
    #pragma unroll
    for (int q = 0; q < 4; ++q) {
        int row = tr * 32 + ry + q * 8;
        tile[ry + q * 8][cx] = ld1<F32>(W, (size_t)row * HD + tc * 32 + cx);
    }
    __syncthreads();
    #pragma unroll
    for (int q = 0; q < 4; ++q) {
        int orow = tc * 32 + ry + q * 8;     // col index in W
        WT[(size_t)orow * HD + tr * 32 + cx] = tile[cx][ry + q * 8];
    }
}
__global__ __launch_bounds__(256) void k_wt(
    const void* Wq, const void* Wk, const void* Wv,
    float* WTq, float* WTk, float* WTv, const int* flag) {
    __shared__ float tile[32][33];
    int m = blockIdx.x >> 4;
    const void* W = (m == 0) ? Wq : (m == 1) ? Wk : Wv;
    float* WT     = (m == 0) ? WTq : (m == 1) ? WTk : WTv;
    if (*flag) wt_body<true >(tile, W, WT);
    else       wt_body<false>(tile, W, WT);
}

// ---------------- Kernel 1: Q/K/V projections (Q pre-scaled by 0.25) ----
// 256 threads: d = tid&127 (output dim), g = tid>>7 (node half). W reads via
// fp32 WT -> coalesced b32 loads; h staged in LDS, broadcast reads.
template<bool F32>
__device__ __forceinline__ void qkv_body(
    float (*hs)[HD],
    const void* __restrict__ h,
    const float* __restrict__ WTq, const void* __restrict__ bq,
    const float* __restrict__ WTk, const void* __restrict__ bk,
    const float* __restrict__ WTv, const void* __restrict__ bv,
    float* __restrict__ Qs, float* __restrict__ Kg, float* __restrict__ Vg)
{
    const int n0 = blockIdx.x * 8;
    const int d = threadIdx.x & 127;
    const int g = threadIdx.x >> 7;          // nodes g*4 .. g*4+3
    #pragma unroll
    for (int r = 0; r < 4; ++r)
        hs[g * 4 + r][d] = ld1<F32>(h, (size_t)(n0 + g * 4 + r) * HD + d);
    __syncthreads();

    float aq[4], ak[4], av[4];
    #pragma unroll
    for (int i = 0; i < 4; ++i) { aq[i] = 0.f; ak[i] = 0.f; av[i] = 0.f; }

    #pragma unroll 4
    for (int c = 0; c < HD; ++c) {
        float wq = WTq[c * HD + d];
        float wk = WTk[c * HD + d];
        float wv = WTv[c * HD + d];
        #pragma unroll
        for (int n = 0; n < 4; ++n) {
            float hv = hs[g * 4 + n][c];     // wave-uniform -> broadcast
            aq[n] += wq * hv;
            ak[n] += wk * hv;
            av[n] += wv * hv;
        }
    }
    const float bqd = ld1<F32>(bq, d), bkd = ld1<F32>(bk, d), bvd = ld1<F32>(bv, d);
    #pragma unroll
    for (int n = 0; n < 4; ++n) {
        size_t o = (size_t)(n0 + g * 4 + n) * HD + d;
        Qs[o] = 0.25f * (aq[n] + bqd);       // fold 1/sqrt(16)
        Kg[o] = ak[n] + bkd;
        Vg[o] = av[n] + bvd;
    }
}

__global__ __launch_bounds__(256) void k_qkv(
    const void* h, const float* WTq, const void* bq, const float* WTk,
    const void* bk, const float* WTv, const void* bv,
    float* Qs, float* Kg, float* Vg, const int* flag)
{
    __shared__ float hs[8][HD];
    if (*flag) qkv_body<true >(hs, h, WTq, bq, WTk, bk, WTv, bv, Qs, Kg, Vg);
    else       qkv_body<false>(hs, h, WTq, bq, WTk, bk, WTv, bv, Qs, Kg, Vg);
}

// ---------------- Kernel 2a: histogram of dst ----
__global__ void k_hist(const int* __restrict__ dst, int* __restrict__ cnt) {
    int i = blockIdx.x * blockDim.x + threadIdx.x;
    if (i < N_EDGES) {
        int d = dst[i];
        d = max(0, min(d, N_NODES - 1));
        atomicAdd(&cnt[d], 1);
    }
}

// ---------------- Kernel 2b: exclusive scan (wave-shuffle version) ----
__global__ __launch_bounds__(1024) void k_scan(const int* __restrict__ cnt,
                                               int* __restrict__ cursor) {
    __shared__ int wsum[16];
    const int tid = threadIdx.x;
    const int lane = tid & 63, wv = tid >> 6;
    int carry = 0;
    for (int base = 0; base < N_NODES; base += 1024) {
        int i = base + tid;
        int v = (i < N_NODES) ? cnt[i] : 0;
        int s = v;                            // inclusive wave scan
        #pragma unroll
        for (int off = 1; off < 64; off <<= 1) {
            int t = __shfl_up(s, off);
            if (lane >= off) s += t;
        }
        if (lane == 63) wsum[wv] = s;
        __syncthreads();
        if (wv == 0) {
            int wsv = (lane < 16) ? wsum[lane] : 0;
            #pragma unroll
            for (int off = 1; off < 16; off <<= 1) {
                int t = __shfl_up(wsv, off);
                if (lane >= off) wsv += t;
            }
            if (lane < 16) wsum[lane] = wsv;
        }
        __syncthreads();
        int wbase = (wv == 0) ? 0 : wsum[wv - 1];
        if (i < N_NODES) cursor[i] = carry + wbase + s - v;
        carry += wsum[15];
        __syncthreads();                      // protect wsum for next chunk
    }
}

// ---------------- Kernel 2c: bucket placement -> dst-sorted edge ids ----
__global__ void k_place(const int* __restrict__ dst, int* __restrict__ cursor,
                        int* __restrict__ eorder) {
    int i = blockIdx.x * blockDim.x + threadIdx.x;
    if (i < N_EDGES) {
        int d = dst[i];
        d = max(0, min(d, N_NODES - 1));
        int pos = atomicAdd(&cursor[d], 1);
        pos = max(0, min(pos, N_EDGES - 1));
        eorder[pos] = i;
    }
}

// ---------------- Kernel 3: fused E-projection + score + segment-reduce ----
// v2: We MFMA B-fragments live in registers (2 heads per wave, loaded once
// per block); LDS holds only the gathered e tile + scores + ids.
// LDS 55.8KB -> 20.2KB, occupancy 23% -> ~50%.
struct EdgeSmem {
    unsigned short Ae[64][TPAD];    // gathered e rows (bf16)
    float sc[64][NH];               // score_soft per edge/head
    int eids[64], srcs[64], dsts[64];
};

template<bool F32>
__device__ __forceinline__ void edge_body(
    EdgeSmem& sm,
    const void* __restrict__ e,
    const void* __restrict__ We, const void* __restrict__ be,
    const int* __restrict__ src, const int* __restrict__ dst,
    const int* __restrict__ eorder,
    const float* __restrict__ Qs, const float* __restrict__ Kg,
    const float* __restrict__ Vg,
    float* __restrict__ wV, float* __restrict__ zacc)
{
    const int tid = threadIdx.x;
    const int tile = blockIdx.x;
    const int lane = tid & 63;
    const int w = tid >> 6;
    const int col = lane & 15;
    const int lq = lane >> 4;

    if (tid < 64) {
        int eid = eorder[tile * 64 + tid];
        eid = max(0, min(eid, N_EDGES - 1));          // defensive clamp
        sm.eids[tid] = eid;
        int s = src[eid]; sm.srcs[tid] = max(0, min(s, N_NODES - 1));
        int d = dst[eid]; sm.dsts[tid] = max(0, min(d, N_NODES - 1));
    }

    // We fragments -> registers; wave w owns heads {2w, 2w+1}.
    // Per lane: We[row=hh*16+col][kt*32+lq*8 .. +8] (identical per-lane data
    // to the previously verified LDS-staged B-fragment).
    uint4 wfr[2][4];
    float bev[2];
    #pragma unroll
    for (int hp = 0; hp < 2; ++hp) {
        int row = (w * 2 + hp) * 16 + col;
        bev[hp] = ld1<F32>(be, row);
        #pragma unroll
        for (int kt = 0; kt < 4; ++kt)
            wfr[hp][kt] = ld8b<F32>(We, (size_t)row * HD + kt * 32 + lq * 8);
    }
    __syncthreads();
    {   // stage gathered e rows: thread -> row tid>>2, quarter tid&3 (32 elems)
        int row = tid >> 2, qq = tid & 3;
        size_t base = (size_t)sm.eids[row] * HD + qq * 32;
        uint4* lp = (uint4*)&sm.Ae[row][qq * 32];
        #pragma unroll
        for (int q = 0; q < 4; ++q)
            lp[q] = ld8b<F32>(e, base + q * 8);
    }
    __syncthreads();

    // ---- phase 1: wave w computes its 2 heads over all 4 edge-groups ----
    #pragma unroll
    for (int hp = 0; hp < 2; ++hp) {
        const int hh = w * 2 + hp;
        #pragma unroll
        for (int g = 0; g < 4; ++g) {
            floatx4 acc = {0.f, 0.f, 0.f, 0.f};
            #pragma unroll
            for (int kt = 0; kt < 4; ++kt) {
                bf16x8 a = *(const bf16x8*)&sm.Ae[g * 16 + col][kt * 32 + lq * 8];
                bf16x8 b = *(const bf16x8*)&wfr[hp][kt];
                acc = __builtin_amdgcn_mfma_f32_16x16x32_bf16(a, b, acc, 0, 0, 0);
            }
            #pragma unroll
            for (int r = 0; r < 4; ++r) {
                int edge = g * 16 + lq * 4 + r;
                int s_n = sm.srcs[edge], d_n = sm.dsts[edge];
                float kq = Kg[(size_t)s_n * HD + hh * 16 + col] *
                           Qs[(size_t)d_n * HD + hh * 16 + col];
                float p = (acc[r] + bev[hp]) * kq;
                p += __shfl_xor(p, 1);
                p += __shfl_xor(p, 2);
                p += __shfl_xor(p, 4);
                p += __shfl_xor(p, 8);
                if (col == 0) {
                    p = fminf(fmaxf(p, -5.f), 5.f);
                    sm.sc[edge][hh] = __expf(p);
                }
            }
        }
    }
    __syncthreads();

    // ---- phase 2: segmented accumulation (edges sorted by dst) ----
    const int halfsel = tid >> 7;      // 0..1 -> 32 edges each
    const int hd = tid & 127;
    const int hhead = hd >> 4;
    const int e0 = halfsel * 32;

    float vv[32];
    #pragma unroll
    for (int i = 0; i < 32; ++i)
        vv[i] = Vg[(size_t)sm.srcs[e0 + i] * HD + hd];

    float accv = 0.f, accz = 0.f;
    int cur = sm.dsts[e0];
    #pragma unroll
    for (int i = 0; i < 32; ++i) {
        int ed = e0 + i;
        int dn = sm.dsts[ed];
        if (dn != cur) {               // wave-uniform branch
            atomicAdd(&wV[(size_t)cur * HD + hd], accv);
            if ((hd & 15) == 0) atomicAdd(&zacc[cur * NH + hhead], accz);
            accv = 0.f; accz = 0.f; cur = dn;
        }
        float s = sm.sc[ed][hhead];
        accv += s * vv[i];
        accz += s;
    }
    atomicAdd(&wV[(size_t)cur * HD + hd], accv);
    if ((hd & 15) == 0) atomicAdd(&zacc[cur * NH + hhead], accz);
}

__global__ __launch_bounds__(256, 4) void k_edge(
    const void* e, const void* We, const void* be,
    const int* src, const int* dst, const int* eorder,
    const float* Qs, const float* Kg, const float* Vg,
    float* wV, float* zacc, const int* flag)
{
    __shared__ EdgeSmem sm;
    if (*flag) edge_body<true >(sm, e, We, be, src, dst, eorder, Qs, Kg, Vg, wV, zacc);
    else       edge_body<false>(sm, e, We, be, src, dst, eorder, Qs, Kg, Vg, wV, zacc);
}

// ---------------- Kernel 4: normalize + cast -------------------------------
__global__ void k_final(const float* __restrict__ wV, const float* __restrict__ zacc,
                        void* __restrict__ out, const int* __restrict__ flag) {
    int i = blockIdx.x * blockDim.x + threadIdx.x;
    if (i < N_NODES * HD) {
        int node = i >> 7;
        int hh = (i & 127) >> 4;
        float v = wV[i] / (zacc[node * NH + hh] + 1e-6f);
        if (*flag) ((float*)out)[i] = v;
        else       ((unsigned short*)out)[i] = f2b(v);
    }
}

extern "C" void kernel_launch(void* const* d_in, const int* in_sizes, int n_in,
                              void* d_out, int out_size, void* d_ws, size_t ws_size,
                              hipStream_t stream) {
    const void* h  = d_in[0];
    const void* e  = d_in[1];
    const int* src = (const int*)d_in[2];
    const int* dst = (const int*)d_in[3];
    const void* Wq = d_in[4];
    const void* bq = d_in[5];
    const void* Wk = d_in[6];
    const void* bk = d_in[7];
    const void* We = d_in[8];
    const void* be = d_in[9];
    const void* Wv = d_in[10];
    const void* bv = d_in[11];

    char* ws = (char*)d_ws;
    float* Qs    = (float*)(ws + 0);           //  5,120,000 B
    float* Kg    = (float*)(ws + 5120000);     //  5,120,000 B
    float* Vg    = (float*)(ws + 10240000);    //  5,120,000 B
    int* eorder  = (int*)  (ws + 15360000);    //  2,560,000 B
    int* cursor  = (int*)  (ws + 17920000);    //     40,000 B
    float* wV    = (float*)(ws + 17960000);    //  5,120,000 B (zeroed)
    float* zacc  = (float*)(ws + 23080000);    //    320,000 B (zeroed)
    int* cnt     = (int*)  (ws + 23400000);    //     40,000 B (zeroed)
    int* flag    = (int*)  (ws + 23440000);    //          4 B (zeroed)
    int* wcnt    = (int*)  (ws + 23440004);    //          4 B (zeroed)
    // WT buffers live INSIDE the eorder region (lifetimes disjoint:
    // k_wt writes WT -> k_qkv reads WT -> later k_place overwrites eorder).
    // Keeps total workspace at the verified 23,440,008 B.
    float* WTq   = (float*)(ws + 15360000);    //     65,536 B
    float* WTk   = (float*)(ws + 15425536);    //     65,536 B
    float* WTv   = (float*)(ws + 15491072);    //     65,536 B

    hipMemsetAsync(ws + 17960000, 0, 5480008, stream);

    k_sniff<<<1, 256, 0, stream>>>((const unsigned short*)h, wcnt, flag);
    k_wt<<<48, 256, 0, stream>>>(Wq, Wk, Wv, WTq, WTk, WTv, flag);
    k_qkv<<<N_NODES / 8, 256, 0, stream>>>(h, WTq, bq, WTk, bk, WTv, bv,
                                           Qs, Kg, Vg, flag);
    k_hist<<<(N_EDGES + 255) / 256, 256, 0, stream>>>(dst, cnt);
    k_scan<<<1, 1024, 0, stream>>>(cnt, cursor);
    k_place<<<(N_EDGES + 255) / 256, 256, 0, stream>>>(dst, cursor, eorder);
    k_edge<<<N_EDGES / 64, 256, 0, stream>>>(e, We, be, src, dst, eorder,
                                             Qs, Kg, Vg, wV, zacc, flag);
    k_final<<<(N_NODES * HD + 255) / 256, 256, 0, stream>>>(wV, zacc, d_out, flag);
}

// Round 3
// 962.662 us; speedup vs baseline: 1.0571x; 1.0158x over previous
//
#include <hip/hip_runtime.h>
#include <hip/hip_bf16.h>

#define N_NODES 10000
#define N_EDGES 640000
#define HD 128          // NUM_HEADS * OUT_DIM
#define NH 8
#define TPAD 136        // LDS row pad: 272B stride -> uniform bank spread on b128 reads

typedef __attribute__((ext_vector_type(4))) float floatx4;
typedef __attribute__((ext_vector_type(8))) __bf16 bf16x8;

__device__ __forceinline__ float b2f(unsigned short u) {
    union { unsigned int i; float f; } x;
    x.i = ((unsigned int)u) << 16;
    return x.f;
}
__device__ __forceinline__ unsigned short f2b(float f) {   // RNE bf16
    union { float f; unsigned int i; } x; x.f = f;
    unsigned int r = x.i + 0x7FFF + ((x.i >> 16) & 1);
    return (unsigned short)(r >> 16);
}

template<bool F32>
__device__ __forceinline__ float ld1(const void* p, size_t i) {
    if (F32) return ((const float*)p)[i];
    return b2f(((const unsigned short*)p)[i]);
}
template<bool F32>
__device__ __forceinline__ void ld8(const void* p, size_t i, float* out) {
    if (F32) {
        floatx4 a = *(const floatx4*)((const float*)p + i);
        floatx4 b = *(const floatx4*)((const float*)p + i + 4);
        out[0]=a[0]; out[1]=a[1]; out[2]=a[2]; out[3]=a[3];
        out[4]=b[0]; out[5]=b[1]; out[6]=b[2]; out[7]=b[3];
    } else {
        uint4 u = *(const uint4*)((const unsigned short*)p + i);
        const unsigned short* s = (const unsigned short*)&u;
        #pragma unroll
        for (int j = 0; j < 8; ++j) out[j] = b2f(s[j]);
    }
}
// load 8 elems -> packed bf16 (uint4)
template<bool F32>
__device__ __forceinline__ uint4 ld8b(const void* p, size_t i) {
    if (F32) {
        float f[8]; ld8<true>(p, i, f);
        union { unsigned short s[8]; uint4 u; } r;
        #pragma unroll
        for (int j = 0; j < 8; ++j) r.s[j] = f2b(f[j]);
        return r.u;
    }
    return *(const uint4*)((const unsigned short*)p + i);
}

// ---------------- Kernel 0: dtype sniff (1 block) ----------------
__global__ void k_sniff(const unsigned short* __restrict__ h,
                        int* __restrict__ wcnt, int* __restrict__ flag) {
    int t = threadIdx.x;
    int w = 0;
    #pragma unroll
    for (int j = 0; j < 16; ++j) {
        unsigned short u = h[t * 16 + j];
        int ex = (u >> 7) & 0xFF;
        if (ex >= 0x8F) ++w;
    }
    atomicAdd(wcnt, w);
    __threadfence();
    __syncthreads();
    if (t == 0) {
        int c = atomicAdd(wcnt, 0);
        *flag = (c > 64) ? 1 : 0;   // 1 => inputs (and output) are fp32
    }
}

// ---------------- Kernel 0b: transpose Wq/Wk/Wv -> fp32 WT --------------
// WT[c][d] = W[d][c]; makes k_qkv's W reads coalesced (1 line per wave-load
// instead of 64).
template<bool F32>
__device__ __forceinline__ void wt_body(float (*tile)[33], const void* W,
                                        float* __restrict__ WT) {
    const int t  = blockIdx.x & 15;          // 4x4 tiles of 32x32
    const int tr = t >> 2, tc = t & 3;
    const int cx = threadIdx.x & 31, ry = threadIdx.x >> 5;   // 32 x 8
    #pragma unroll
    for (int q = 0; q < 4; ++q) {
        int row = tr * 32 + ry + q * 8;
        tile[ry + q * 8][cx] = ld1<F32>(W, (size_t)row * HD + tc * 32 + cx);
    }
    __syncthreads();
    #pragma unroll
    for (int q = 0; q < 4; ++q) {
        int orow = tc * 32 + ry + q * 8;     // col index in W
        WT[(size_t)orow * HD + tr * 32 + cx] = tile[cx][ry + q * 8];
    }
}
__global__ __launch_bounds__(256) void k_wt(
    const void* Wq, const void* Wk, const void* Wv,
    float* WTq, float* WTk, float* WTv, const int* flag) {
    __shared__ float tile[32][33];
    int m = blockIdx.x >> 4;
    const void* W = (m == 0) ? Wq : (m == 1) ? Wk : Wv;
    float* WT     = (m == 0) ? WTq : (m == 1) ? WTk : WTv;
    if (*flag) wt_body<true >(tile, W, WT);
    else       wt_body<false>(tile, W, WT);
}

// ---------------- Kernel 1: Q/K/V projections (Q pre-scaled by 0.25) ----
// 256 threads: d = tid&127 (output dim), g = tid>>7 (node half). W reads via
// fp32 WT -> coalesced b32 loads; h staged in LDS, broadcast reads.
template<bool F32>
__device__ __forceinline__ void qkv_body(
    float (*hs)[HD],
    const void* __restrict__ h,
    const float* __restrict__ WTq, const void* __restrict__ bq,
    const float* __restrict__ WTk, const void* __restrict__ bk,
    const float* __restrict__ WTv, const void* __restrict__ bv,
    float* __restrict__ Qs, float* __restrict__ Kg, float* __restrict__ Vg)
{
    const int n0 = blockIdx.x * 8;
    const int d = threadIdx.x & 127;
    const int g = threadIdx.x >> 7;          // nodes g*4 .. g*4+3
    #pragma unroll
    for (int r = 0; r < 4; ++r)
        hs[g * 4 + r][d] = ld1<F32>(h, (size_t)(n0 + g * 4 + r) * HD + d);
    __syncthreads();

    float aq[4], ak[4], av[4];
    #pragma unroll
    for (int i = 0; i < 4; ++i) { aq[i] = 0.f; ak[i] = 0.f; av[i] = 0.f; }

    #pragma unroll 4
    for (int c = 0; c < HD; ++c) {
        float wq = WTq[c * HD + d];
        float wk = WTk[c * HD + d];
        float wv = WTv[c * HD + d];
        #pragma unroll
        for (int n = 0; n < 4; ++n) {
            float hv = hs[g * 4 + n][c];     // wave-uniform -> broadcast
            aq[n] += wq * hv;
            ak[n] += wk * hv;
            av[n] += wv * hv;
        }
    }
    const float bqd = ld1<F32>(bq, d), bkd = ld1<F32>(bk, d), bvd = ld1<F32>(bv, d);
    #pragma unroll
    for (int n = 0; n < 4; ++n) {
        size_t o = (size_t)(n0 + g * 4 + n) * HD + d;
        Qs[o] = 0.25f * (aq[n] + bqd);       // fold 1/sqrt(16)
        Kg[o] = ak[n] + bkd;
        Vg[o] = av[n] + bvd;
    }
}

__global__ __launch_bounds__(256) void k_qkv(
    const void* h, const float* WTq, const void* bq, const float* WTk,
    const void* bk, const float* WTv, const void* bv,
    float* Qs, float* Kg, float* Vg, const int* flag)
{
    __shared__ float hs[8][HD];
    if (*flag) qkv_body<true >(hs, h, WTq, bq, WTk, bk, WTv, bv, Qs, Kg, Vg);
    else       qkv_body<false>(hs, h, WTq, bq, WTk, bk, WTv, bv, Qs, Kg, Vg);
}

// ---------------- Kernel 2a: histogram of dst ----
__global__ void k_hist(const int* __restrict__ dst, int* __restrict__ cnt) {
    int i = blockIdx.x * blockDim.x + threadIdx.x;
    if (i < N_EDGES) {
        int d = dst[i];
        d = max(0, min(d, N_NODES - 1));
        atomicAdd(&cnt[d], 1);
    }
}

// ---------------- Kernel 2b: exclusive scan (wave-shuffle version) ----
__global__ __launch_bounds__(1024) void k_scan(const int* __restrict__ cnt,
                                               int* __restrict__ cursor) {
    __shared__ int wsum[16];
    const int tid = threadIdx.x;
    const int lane = tid & 63, wv = tid >> 6;
    int carry = 0;
    for (int base = 0; base < N_NODES; base += 1024) {
        int i = base + tid;
        int v = (i < N_NODES) ? cnt[i] : 0;
        int s = v;                            // inclusive wave scan
        #pragma unroll
        for (int off = 1; off < 64; off <<= 1) {
            int t = __shfl_up(s, off);
            if (lane >= off) s += t;
        }
        if (lane == 63) wsum[wv] = s;
        __syncthreads();
        if (wv == 0) {
            int wsv = (lane < 16) ? wsum[lane] : 0;
            #pragma unroll
            for (int off = 1; off < 16; off <<= 1) {
                int t = __shfl_up(wsv, off);
                if (lane >= off) wsv += t;
            }
            if (lane < 16) wsum[lane] = wsv;
        }
        __syncthreads();
        int wbase = (wv == 0) ? 0 : wsum[wv - 1];
        if (i < N_NODES) cursor[i] = carry + wbase + s - v;
        carry += wsum[15];
        __syncthreads();                      // protect wsum for next chunk
    }
}

// ---------------- Kernel 2c: bucket placement -> dst-sorted edge ids ----
__global__ void k_place(const int* __restrict__ dst, int* __restrict__ cursor,
                        int* __restrict__ eorder) {
    int i = blockIdx.x * blockDim.x + threadIdx.x;
    if (i < N_EDGES) {
        int d = dst[i];
        d = max(0, min(d, N_NODES - 1));
        int pos = atomicAdd(&cursor[d], 1);
        pos = max(0, min(pos, N_EDGES - 1));
        eorder[pos] = i;
    }
}

// ---------------- Kernel 3: fused E-projection + score + segment-reduce ----
// v3: same structure as v2 (We fragments in registers, 2 heads/wave) but
// spill-free: launch_bounds min-waves=2 lifts the VGPR cap to 256 (v2's
// allocator targeted LDS-allowed occupancy, capped at 64 VGPR and spilled
// ~14KB/wave to scratch -> +1GB HBM traffic), and phase-2's V prefetch is
// chunked 4x8 instead of a 32-deep register array.
struct EdgeSmem {
    unsigned short Ae[64][TPAD];    // gathered e rows (bf16)
    float sc[64][NH];               // score_soft per edge/head
    int eids[64], srcs[64], dsts[64];
};

template<bool F32>
__device__ __forceinline__ void edge_body(
    EdgeSmem& sm,
    const void* __restrict__ e,
    const void* __restrict__ We, const void* __restrict__ be,
    const int* __restrict__ src, const int* __restrict__ dst,
    const int* __restrict__ eorder,
    const float* __restrict__ Qs, const float* __restrict__ Kg,
    const float* __restrict__ Vg,
    float* __restrict__ wV, float* __restrict__ zacc)
{
    const int tid = threadIdx.x;
    const int tile = blockIdx.x;
    const int lane = tid & 63;
    const int w = tid >> 6;
    const int col = lane & 15;
    const int lq = lane >> 4;

    if (tid < 64) {
        int eid = eorder[tile * 64 + tid];
        eid = max(0, min(eid, N_EDGES - 1));          // defensive clamp
        sm.eids[tid] = eid;
        int s = src[eid]; sm.srcs[tid] = max(0, min(s, N_NODES - 1));
        int d = dst[eid]; sm.dsts[tid] = max(0, min(d, N_NODES - 1));
    }

    // We fragments -> registers; wave w owns heads {2w, 2w+1}.
    uint4 wfr[2][4];
    float bev[2];
    #pragma unroll
    for (int hp = 0; hp < 2; ++hp) {
        int row = (w * 2 + hp) * 16 + col;
        bev[hp] = ld1<F32>(be, row);
        #pragma unroll
        for (int kt = 0; kt < 4; ++kt)
            wfr[hp][kt] = ld8b<F32>(We, (size_t)row * HD + kt * 32 + lq * 8);
    }
    __syncthreads();
    {   // stage gathered e rows: thread -> row tid>>2, quarter tid&3 (32 elems)
        int row = tid >> 2, qq = tid & 3;
        size_t base = (size_t)sm.eids[row] * HD + qq * 32;
        uint4* lp = (uint4*)&sm.Ae[row][qq * 32];
        #pragma unroll
        for (int q = 0; q < 4; ++q)
            lp[q] = ld8b<F32>(e, base + q * 8);
    }
    __syncthreads();

    // ---- phase 1: wave w computes its 2 heads over all 4 edge-groups ----
    #pragma unroll
    for (int hp = 0; hp < 2; ++hp) {
        const int hh = w * 2 + hp;
        #pragma unroll
        for (int g = 0; g < 4; ++g) {
            floatx4 acc = {0.f, 0.f, 0.f, 0.f};
            #pragma unroll
            for (int kt = 0; kt < 4; ++kt) {
                bf16x8 a = *(const bf16x8*)&sm.Ae[g * 16 + col][kt * 32 + lq * 8];
                bf16x8 b = *(const bf16x8*)&wfr[hp][kt];
                acc = __builtin_amdgcn_mfma_f32_16x16x32_bf16(a, b, acc, 0, 0, 0);
            }
            #pragma unroll
            for (int r = 0; r < 4; ++r) {
                int edge = g * 16 + lq * 4 + r;
                int s_n = sm.srcs[edge], d_n = sm.dsts[edge];
                float kq = Kg[(size_t)s_n * HD + hh * 16 + col] *
                           Qs[(size_t)d_n * HD + hh * 16 + col];
                float p = (acc[r] + bev[hp]) * kq;
                p += __shfl_xor(p, 1);
                p += __shfl_xor(p, 2);
                p += __shfl_xor(p, 4);
                p += __shfl_xor(p, 8);
                if (col == 0) {
                    p = fminf(fmaxf(p, -5.f), 5.f);
                    sm.sc[edge][hh] = __expf(p);
                }
            }
        }
    }
    __syncthreads();

    // ---- phase 2: segmented accumulation (edges sorted by dst) ----
    // Chunked 4x8 V prefetch: 8 in-flight gathers hide L2 latency without
    // a 32-deep register array (v2 spilled it to scratch).
    const int halfsel = tid >> 7;      // 0..1 -> 32 edges each
    const int hd = tid & 127;
    const int hhead = hd >> 4;
    const int e0 = halfsel * 32;

    float accv = 0.f, accz = 0.f;
    int cur = sm.dsts[e0];
    #pragma unroll 1
    for (int c4 = 0; c4 < 4; ++c4) {
        float vv[8];
        #pragma unroll
        for (int i = 0; i < 8; ++i)
            vv[i] = Vg[(size_t)sm.srcs[e0 + c4 * 8 + i] * HD + hd];
        #pragma unroll
        for (int i = 0; i < 8; ++i) {
            int ed = e0 + c4 * 8 + i;
            int dn = sm.dsts[ed];
            if (dn != cur) {               // wave-uniform branch
                atomicAdd(&wV[(size_t)cur * HD + hd], accv);
                if ((hd & 15) == 0) atomicAdd(&zacc[cur * NH + hhead], accz);
                accv = 0.f; accz = 0.f; cur = dn;
            }
            float s = sm.sc[ed][hhead];
            accv += s * vv[i];
            accz += s;
        }
    }
    atomicAdd(&wV[(size_t)cur * HD + hd], accv);
    if ((hd & 15) == 0) atomicAdd(&zacc[cur * NH + hhead], accz);
}

__global__ __launch_bounds__(256, 2) void k_edge(
    const void* e, const void* We, const void* be,
    const int* src, const int* dst, const int* eorder,
    const float* Qs, const float* Kg, const float* Vg,
    float* wV, float* zacc, const int* flag)
{
    __shared__ EdgeSmem sm;
    if (*flag) edge_body<true >(sm, e, We, be, src, dst, eorder, Qs, Kg, Vg, wV, zacc);
    else       edge_body<false>(sm, e, We, be, src, dst, eorder, Qs, Kg, Vg, wV, zacc);
}

// ---------------- Kernel 4: normalize + cast -------------------------------
__global__ void k_final(const float* __restrict__ wV, const float* __restrict__ zacc,
                        void* __restrict__ out, const int* __restrict__ flag) {
    int i = blockIdx.x * blockDim.x + threadIdx.x;
    if (i < N_NODES * HD) {
        int node = i >> 7;
        int hh = (i & 127) >> 4;
        float v = wV[i] / (zacc[node * NH + hh] + 1e-6f);
        if (*flag) ((float*)out)[i] = v;
        else       ((unsigned short*)out)[i] = f2b(v);
    }
}

extern "C" void kernel_launch(void* const* d_in, const int* in_sizes, int n_in,
                              void* d_out, int out_size, void* d_ws, size_t ws_size,
                              hipStream_t stream) {
    const void* h  = d_in[0];
    const void* e  = d_in[1];
    const int* src = (const int*)d_in[2];
    const int* dst = (const int*)d_in[3];
    const void* Wq = d_in[4];
    const void* bq = d_in[5];
    const void* Wk = d_in[6];
    const void* bk = d_in[7];
    const void* We = d_in[8];
    const void* be = d_in[9];
    const void* Wv = d_in[10];
    const void* bv = d_in[11];

    char* ws = (char*)d_ws;
    float* Qs    = (float*)(ws + 0);           //  5,120,000 B
    float* Kg    = (float*)(ws + 5120000);     //  5,120,000 B
    float* Vg    = (float*)(ws + 10240000);    //  5,120,000 B
    int* eorder  = (int*)  (ws + 15360000);    //  2,560,000 B
    int* cursor  = (int*)  (ws + 17920000);    //     40,000 B
    float* wV    = (float*)(ws + 17960000);    //  5,120,000 B (zeroed)
    float* zacc  = (float*)(ws + 23080000);    //    320,000 B (zeroed)
    int* cnt     = (int*)  (ws + 23400000);    //     40,000 B (zeroed)
    int* flag    = (int*)  (ws + 23440000);    //          4 B (zeroed)
    int* wcnt    = (int*)  (ws + 23440004);    //          4 B (zeroed)
    // WT buffers live INSIDE the eorder region (lifetimes disjoint:
    // k_wt writes WT -> k_qkv reads WT -> later k_place overwrites eorder).
    float* WTq   = (float*)(ws + 15360000);    //     65,536 B
    float* WTk   = (float*)(ws + 15425536);    //     65,536 B
    float* WTv   = (float*)(ws + 15491072);    //     65,536 B

    hipMemsetAsync(ws + 17960000, 0, 5480008, stream);

    k_sniff<<<1, 256, 0, stream>>>((const unsigned short*)h, wcnt, flag);
    k_wt<<<48, 256, 0, stream>>>(Wq, Wk, Wv, WTq, WTk, WTv, flag);
    k_qkv<<<N_NODES / 8, 256, 0, stream>>>(h, WTq, bq, WTk, bk, WTv, bv,
                                           Qs, Kg, Vg, flag);
    k_hist<<<(N_EDGES + 255) / 256, 256, 0, stream>>>(dst, cnt);
    k_scan<<<1, 1024, 0, stream>>>(cnt, cursor);
    k_place<<<(N_EDGES + 255) / 256, 256, 0, stream>>>(dst, cursor, eorder);
    k_edge<<<N_EDGES / 64, 256, 0, stream>>>(e, We, be, src, dst, eorder,
                                             Qs, Kg, Vg, wV, zacc, flag);
    k_final<<<(N_NODES * HD + 255) / 256, 256, 0, stream>>>(wV, zacc, d_out, flag);
}